// Round 9
// baseline (273.445 us; speedup 1.0000x reference)
//
#include <hip/hip_runtime.h>

#define BB 8192
#define TT 512
#define II 5
#define HH 16
#define TC 32                       // steps per LDS chunk
#define NC (TT / TC)                // 16 chunks
#define CHUNK_BYTES (16 * TC * 32)  // per chain: 16 batches * 32 steps * 32B

typedef _Float16 half_t;
typedef _Float16 half4 __attribute__((ext_vector_type(4)));
typedef __fp16 fp16x2 __attribute__((ext_vector_type(2)));
typedef float floatx4 __attribute__((ext_vector_type(4)));
typedef unsigned int uint32;
typedef uint32 uint2v __attribute__((ext_vector_type(2)));

__device__ __forceinline__ float fast_sigmoid(float x) {
    float e = __builtin_amdgcn_exp2f(x * -1.4426950408889634f);
    return __builtin_amdgcn_rcpf(1.0f + e);
}
__device__ __forceinline__ float fast_tanh(float x) {
    float e = __builtin_amdgcn_exp2f(x * 2.8853900817779268f);
    return fmaf(-2.0f, __builtin_amdgcn_rcpf(e + 1.0f), 1.0f);
}

__device__ __forceinline__ void gl_lds16(const void* g, void* l) {
    __builtin_amdgcn_global_load_lds(
        (const __attribute__((address_space(1))) void*)g,
        (__attribute__((address_space(3))) void*)l, 16, 0, 0);
}

// Per-wave GRU: TWO independent 16-batch chains (A/B) interleaved in one
// wave (32 batches / wave, 256 blocks = 1/CU). The serial per-step
// dependency bubbles (MFMA->VALU hazards, trans latency) of chain A are
// filled by chain B's independent instructions. x-side cx MFMAs are
// software-pipelined one step ahead so the d-MFMA's C-input is ready
// (removes one MFMA latency from the serial path).
__global__ __launch_bounds__(64)
void gru_fwd_kernel(const float* __restrict__ x,
                    const float* __restrict__ W_ih,
                    const float* __restrict__ W_hh,
                    const float* __restrict__ b_ih,
                    const float* __restrict__ b_hh,
                    const float* __restrict__ W_fc,
                    const float* __restrict__ b_fc,
                    float* __restrict__ out) {
    __shared__ __align__(16) char ldsA[2][CHUNK_BYTES];
    __shared__ __align__(16) char ldsB[2][CHUNK_BYTES];

    const int lane = threadIdx.x;   // 0..63
    const int jb   = lane & 15;     // batch within tile (B/D column, A row)
    const int q    = lane >> 4;     // k-group
    const int b0   = blockIdx.x * 32;   // chain A: b0+jb, chain B: b0+16+jb

    // ---- resident A-fragments (shared by both chains)
    half4 wa_r, wa_z, wa_n, wx_r, wx_z, wx_n;
#pragma unroll
    for (int j = 0; j < 4; ++j) {
        int k = 4 * q + j;
        wa_r[j] = (half_t)W_hh[(0 * HH + jb) * HH + k];
        wa_z[j] = (half_t)W_hh[(1 * HH + jb) * HH + k];
        wa_n[j] = (half_t)W_hh[(2 * HH + jb) * HH + k];
        float vr = (k < II) ? W_ih[(0 * HH + jb) * II + k] : 0.0f;
        float vz = (k < II) ? W_ih[(1 * HH + jb) * II + k] : 0.0f;
        float vn = (k < II) ? W_ih[(2 * HH + jb) * II + k] : 0.0f;
        wx_r[j] = (half_t)vr; wx_z[j] = (half_t)vz; wx_n[j] = (half_t)vn;
    }

    floatx4 cb_r, cb_z, cb_xn, cb_hn;
#pragma unroll
    for (int i = 0; i < 4; ++i) {
        int r = 4 * q + i;
        cb_r[i]  = b_ih[r] + b_hh[r];
        cb_z[i]  = b_ih[HH + r] + b_hh[HH + r];
        cb_xn[i] = b_ih[2 * HH + r];
        cb_hn[i] = b_hh[2 * HH + r];
    }

    // ---- per-chain loop-carried state
    half4 bhA = {}, bhB = {};
    float hA0 = 0.f, hA1 = 0.f, hA2 = 0.f, hA3 = 0.f;
    float hB0 = 0.f, hB1 = 0.f, hB2 = 0.f, hB3 = 0.f;

    // ---- DMA source swizzle (as R7/R8): LDS slot l of batch k holds
    // record-part (s,h) with l' = l ^ (k&7).
    int off8[8];
#pragma unroll
    for (int m = 0; m < 8; ++m) {
        int lp = lane ^ m;
        off8[m] = (lp >> 1) * (II * 4) + (lp & 1) * 4;
    }

#define ISSUE(C)                                                              \
    do {                                                                      \
        if ((C) < NC) {                                                       \
            const char* cbase_ = (const char*)x                               \
                + ((size_t)b0 * TT + (size_t)(C) * TC) * (II * 4);            \
            _Pragma("unroll")                                                 \
            for (int k_ = 0; k_ < 32; ++k_) {                                 \
                char* db_ = (k_ < 16 ? &ldsA[(C) & 1][0] : &ldsB[(C) & 1][0]) \
                          + (k_ & 15) * 1024;                                 \
                gl_lds16(cbase_ + (size_t)k_ * (TT * II * 4) + off8[k_ & 7],  \
                         db_);                                                \
            }                                                                 \
        }                                                                     \
    } while (0)

    // x-side MFMAs for one step (independent of h): PF -> CXR/CXZ/CXN
#define PREP(PF, CXR, CXZ, CXN)                                               \
    do {                                                                      \
        fp16x2 pk01_ = __builtin_amdgcn_cvt_pkrtz(PF[0], PF[1]);              \
        fp16x2 pk23_ = __builtin_amdgcn_cvt_pkrtz(PF[2], PF[3]);              \
        fp16x2 pk4_  = __builtin_amdgcn_cvt_pkrtz(PF[3], 0.0f);               \
        uint32 lo_ = (q == 0) ? __builtin_bit_cast(uint32, pk01_)             \
                   : ((q == 1) ? __builtin_bit_cast(uint32, pk4_) : 0u);      \
        uint32 hi_ = (q == 0) ? __builtin_bit_cast(uint32, pk23_) : 0u;       \
        uint2v bxu_ = {lo_, hi_};                                             \
        half4 bx_ = __builtin_bit_cast(half4, bxu_);                          \
        CXR = __builtin_amdgcn_mfma_f32_16x16x16f16(wx_r, bx_, cb_r, 0, 0, 0);\
        CXZ = __builtin_amdgcn_mfma_f32_16x16x16f16(wx_z, bx_, cb_z, 0, 0, 0);\
        CXN = __builtin_amdgcn_mfma_f32_16x16x16f16(wx_n, bx_, cb_xn, 0, 0, 0);\
    } while (0)

    // h-side MFMAs + gates + state update for one step of one chain
#define GATE(BH, H0, H1, H2, H3, CXR, CXZ, CXN)                               \
    do {                                                                      \
        floatx4 d_r = __builtin_amdgcn_mfma_f32_16x16x16f16(wa_r, BH, CXR, 0, 0, 0); \
        floatx4 d_z = __builtin_amdgcn_mfma_f32_16x16x16f16(wa_z, BH, CXZ, 0, 0, 0); \
        floatx4 d_n = __builtin_amdgcn_mfma_f32_16x16x16f16(wa_n, BH, cb_hn, 0, 0, 0); \
        float r0 = fast_sigmoid(d_r[0]), z0 = fast_sigmoid(d_z[0]);           \
        float n0 = fast_tanh(fmaf(r0, d_n[0], CXN[0]));                       \
        H0 = fmaf(z0, H0 - n0, n0);                                           \
        float r1 = fast_sigmoid(d_r[1]), z1 = fast_sigmoid(d_z[1]);           \
        float n1 = fast_tanh(fmaf(r1, d_n[1], CXN[1]));                       \
        H1 = fmaf(z1, H1 - n1, n1);                                           \
        float r2 = fast_sigmoid(d_r[2]), z2 = fast_sigmoid(d_z[2]);           \
        float n2 = fast_tanh(fmaf(r2, d_n[2], CXN[2]));                       \
        H2 = fmaf(z2, H2 - n2, n2);                                           \
        float r3 = fast_sigmoid(d_r[3]), z3 = fast_sigmoid(d_z[3]);           \
        float n3 = fast_tanh(fmaf(r3, d_n[3], CXN[3]));                       \
        H3 = fmaf(z3, H3 - n3, n3);                                           \
        fp16x2 lo2_ = __builtin_amdgcn_cvt_pkrtz(H0, H1);                     \
        fp16x2 hi2_ = __builtin_amdgcn_cvt_pkrtz(H2, H3);                     \
        BH[0] = (half_t)lo2_[0]; BH[1] = (half_t)lo2_[1];                     \
        BH[2] = (half_t)hi2_[0]; BH[3] = (half_t)hi2_[1];                     \
    } while (0)

    ISSUE(0);
    ISSUE(1);

    // Read-side swizzle constants (match write-side involution)
    const int swz   = (jb & 7) << 4;
    const int lobit = ((q & 1) * 16) ^ (swz & 16);
    const int swzhi = swz & 96;

#define RD(REC, S) (*(const floatx4*)((REC) + ((((S) & 31) * 32) ^ swzhi)))

    for (int c = 0; c < NC; ++c) {
        // Wait for chunk c's 32 loads; keep chunk c+1's 32 in flight.
        if (c == NC - 1) asm volatile("s_waitcnt vmcnt(0)" ::: "memory");
        else             asm volatile("s_waitcnt vmcnt(32)" ::: "memory");

        const char* recA = &ldsA[c & 1][0] + jb * 1024 + lobit;
        const char* recB = &ldsB[c & 1][0] + jb * 1024 + lobit;

        floatx4 pA0 = RD(recA, 0), pB0 = RD(recB, 0);
        floatx4 pA1 = RD(recA, 1), pB1 = RD(recB, 1);
        floatx4 cAr, cAz, cAn, cBr, cBz, cBn;     // cx for even step
        floatx4 dAr, dAz, dAn, dBr, dBz, dBn;     // cx for odd step
        PREP(pA0, cAr, cAz, cAn);                 // step 0
        PREP(pB0, cBr, cBz, cBn);

        // hot body ~2 KB: stays L1 I-cache resident
#pragma unroll 1
        for (int s = 0; s < TC; s += 2) {
            PREP(pA1, dAr, dAz, dAn);             // cx for step s+1
            PREP(pB1, dBr, dBz, dBn);
            GATE(bhA, hA0, hA1, hA2, hA3, cAr, cAz, cAn);   // step s
            GATE(bhB, hB0, hB1, hB2, hB3, cBr, cBz, cBn);
            pA0 = RD(recA, s + 2); pB0 = RD(recB, s + 2);   // wrap-dead at end
            PREP(pA0, cAr, cAz, cAn);             // cx for step s+2 (dead on last iter)
            PREP(pB0, cBr, cBz, cBn);
            GATE(bhA, hA0, hA1, hA2, hA3, dAr, dAz, dAn);   // step s+1
            GATE(bhB, hB0, hB1, hB2, hB3, dBr, dBz, dBn);
            pA1 = RD(recA, s + 3); pB1 = RD(recB, s + 3);   // wrap-dead at end
        }

        ISSUE(c + 2);   // after all reads of buf[c&1]
    }
#undef ISSUE
#undef PREP
#undef GATE
#undef RD

    // ---- out = dot(W_fc, h) + b_fc ; reduce across the 4 k-groups
    float pA = hA0 * W_fc[4 * q + 0];
    pA = fmaf(hA1, W_fc[4 * q + 1], pA);
    pA = fmaf(hA2, W_fc[4 * q + 2], pA);
    pA = fmaf(hA3, W_fc[4 * q + 3], pA);
    pA += __shfl_xor(pA, 16);
    pA += __shfl_xor(pA, 32);

    float pB = hB0 * W_fc[4 * q + 0];
    pB = fmaf(hB1, W_fc[4 * q + 1], pB);
    pB = fmaf(hB2, W_fc[4 * q + 2], pB);
    pB = fmaf(hB3, W_fc[4 * q + 3], pB);
    pB += __shfl_xor(pB, 16);
    pB += __shfl_xor(pB, 32);

    if (q == 0) {
        out[b0 + jb]      = pA + b_fc[0];
        out[b0 + 16 + jb] = pB + b_fc[0];
    }
}

extern "C" void kernel_launch(void* const* d_in, const int* in_sizes, int n_in,
                              void* d_out, int out_size, void* d_ws, size_t ws_size,
                              hipStream_t stream) {
    const float* x    = (const float*)d_in[0];
    const float* W_ih = (const float*)d_in[1];
    const float* W_hh = (const float*)d_in[2];
    const float* b_ih = (const float*)d_in[3];
    const float* b_hh = (const float*)d_in[4];
    const float* W_fc = (const float*)d_in[5];
    const float* b_fc = (const float*)d_in[6];
    float* out = (float*)d_out;

    dim3 grid(BB / 32);   // one 64-lane wave per 32 batches (2 chains)
    dim3 block(64);
    gru_fwd_kernel<<<grid, block, 0, stream>>>(x, W_ih, W_hh, b_ih, b_hh, W_fc, b_fc, out);
}

// Round 10
// 130.906 us; speedup vs baseline: 2.0889x; 2.0889x over previous
//
#include <hip/hip_runtime.h>

#define BB 8192
#define TT 512
#define II 5
#define HH 16
#define TC 32                       // steps per LDS chunk
#define NC (TT / TC)                // 16 chunks
#define CHUNK_BYTES (16 * TC * 32)  // 16 batches * 32 steps * 32B records

typedef _Float16 half_t;
typedef _Float16 half8 __attribute__((ext_vector_type(8)));
typedef __fp16 fp16x2 __attribute__((ext_vector_type(2)));
typedef float floatx4 __attribute__((ext_vector_type(4)));
typedef unsigned int uint32;
typedef uint32 uint4v __attribute__((ext_vector_type(4)));

__device__ __forceinline__ void gl_lds16(const void* g, void* l) {
    __builtin_amdgcn_global_load_lds(
        (const __attribute__((address_space(1))) void*)g,
        (__attribute__((address_space(3))) void*)l, 16, 0, 0);
}

// Per-wave GRU, 16 batches/wave, 512 waves. K=32 MFMA fusion: B holds
// [h(16) | xpad(16)] in K; ONE B operand feeds all 4 gate MFMAs
// (r, z fused x+h; n split into h-part and x-part per GRU semantics).
// Activation scalings folded into weights: d_r/d_z = -log2e * gate_arg,
// d_nh/d_nx = 2*log2e * parts, so sigma = rcp(1+exp2(d)) (3 instr) and
// tanh = 1 - 2*rcp(1+exp2(y)) (4 instr). D-layout == B h-slot layout:
// lane (q,jb) computes h rows 4q..4q+3 and feeds them to B j=0..3 in-lane.
__global__ __launch_bounds__(64)
void gru_fwd_kernel(const float* __restrict__ x,
                    const float* __restrict__ W_ih,
                    const float* __restrict__ W_hh,
                    const float* __restrict__ b_ih,
                    const float* __restrict__ b_hh,
                    const float* __restrict__ W_fc,
                    const float* __restrict__ b_fc,
                    float* __restrict__ out) {
    __shared__ __align__(16) char ldsbuf[2][CHUNK_BYTES];

    const int lane = threadIdx.x;   // 0..63
    const int jb   = lane & 15;     // batch within tile (B/D column, A row)
    const int q    = lane >> 4;     // k-group
    const int b0   = blockIdx.x * 16;

    const float SNEG = -1.4426950408889634f;   // -log2(e)  (r,z rows)
    const float CPOS =  2.8853900817779268f;   //  2*log2(e) (n rows)

    // ---- A-fragments, logical k-slots: j<4 -> h[4q+j], j>=4 -> xpad[4q+j-4]
    half8 wa_r, wa_z, wa_nh, wa_nx;
#pragma unroll
    for (int j = 0; j < 8; ++j) {
        if (j < 4) {
            int k = 4 * q + j;                     // h dim
            wa_r[j]  = (half_t)(SNEG * W_hh[(0 * HH + jb) * HH + k]);
            wa_z[j]  = (half_t)(SNEG * W_hh[(1 * HH + jb) * HH + k]);
            wa_nh[j] = (half_t)(CPOS * W_hh[(2 * HH + jb) * HH + k]);
            wa_nx[j] = (half_t)0.0f;
        } else {
            int m = 4 * q + (j - 4);               // xpad dim
            float vr = (m < II) ? W_ih[(0 * HH + jb) * II + m] : 0.0f;
            float vz = (m < II) ? W_ih[(1 * HH + jb) * II + m] : 0.0f;
            float vn = (m < II) ? W_ih[(2 * HH + jb) * II + m] : 0.0f;
            wa_r[j]  = (half_t)(SNEG * vr);
            wa_z[j]  = (half_t)(SNEG * vz);
            wa_nh[j] = (half_t)0.0f;
            wa_nx[j] = (half_t)(CPOS * vn);
        }
    }

    // ---- bias C-fragments (row = 4q+i), scalings folded
    floatx4 cb_r, cb_z, cb_nh, cb_nx;
#pragma unroll
    for (int i = 0; i < 4; ++i) {
        int r = 4 * q + i;
        cb_r[i]  = SNEG * (b_ih[r] + b_hh[r]);
        cb_z[i]  = SNEG * (b_ih[HH + r] + b_hh[HH + r]);
        cb_nh[i] = CPOS * b_hh[2 * HH + r];
        cb_nx[i] = CPOS * b_ih[2 * HH + r];
    }

    // ---- loop-carried state (f32 rows 4q+i)
    float hf0 = 0.f, hf1 = 0.f, hf2 = 0.f, hf3 = 0.f;

    // ---- DMA source swizzle (R8-proven): LDS slot l of batch k holds
    // record-part (s,h) with l' = l ^ (k&7).
    int off8[8];
#pragma unroll
    for (int m = 0; m < 8; ++m) {
        int lp = lane ^ m;
        off8[m] = (lp >> 1) * (II * 4) + (lp & 1) * 4;
    }

#define ISSUE(C)                                                              \
    do {                                                                      \
        if ((C) < NC) {                                                       \
            const char* cb_ = (const char*)x                                  \
                + ((size_t)b0 * TT + (size_t)(C) * TC) * (II * 4);            \
            char* db_ = &ldsbuf[(C) & 1][0];                                  \
            _Pragma("unroll")                                                 \
            for (int k_ = 0; k_ < 16; ++k_)                                   \
                gl_lds16(cb_ + (size_t)k_ * (TT * II * 4) + off8[k_ & 7],     \
                         db_ + k_ * 1024);                                    \
        }                                                                     \
    } while (0)

    // One GRU step; PF = raw 16B record half (q0: x0..x3, q1: x1..x4).
#define STEP(PF)                                                              \
    do {                                                                      \
        fp16x2 hp01_ = __builtin_amdgcn_cvt_pkrtz(hf0, hf1);                  \
        fp16x2 hp23_ = __builtin_amdgcn_cvt_pkrtz(hf2, hf3);                  \
        fp16x2 xa_ = __builtin_amdgcn_cvt_pkrtz(PF[0], PF[1]);                \
        fp16x2 xb_ = __builtin_amdgcn_cvt_pkrtz(PF[2], PF[3]);                \
        fp16x2 xc_ = __builtin_amdgcn_cvt_pkrtz(PF[3], 0.0f);                 \
        uint32 x01_ = (q == 0) ? __builtin_bit_cast(uint32, xa_)              \
                    : ((q == 1) ? __builtin_bit_cast(uint32, xc_) : 0u);      \
        uint32 x23_ = (q == 0) ? __builtin_bit_cast(uint32, xb_) : 0u;        \
        uint4v bu_ = {__builtin_bit_cast(uint32, hp01_),                      \
                      __builtin_bit_cast(uint32, hp23_), x01_, x23_};         \
        half8 bv_ = __builtin_bit_cast(half8, bu_);                           \
        floatx4 d_r  = __builtin_amdgcn_mfma_f32_16x16x32_f16(wa_r,  bv_, cb_r,  0, 0, 0); \
        floatx4 d_z  = __builtin_amdgcn_mfma_f32_16x16x32_f16(wa_z,  bv_, cb_z,  0, 0, 0); \
        floatx4 d_nh = __builtin_amdgcn_mfma_f32_16x16x32_f16(wa_nh, bv_, cb_nh, 0, 0, 0); \
        floatx4 d_nx = __builtin_amdgcn_mfma_f32_16x16x32_f16(wa_nx, bv_, cb_nx, 0, 0, 0); \
        float r0 = __builtin_amdgcn_rcpf(1.0f + __builtin_amdgcn_exp2f(d_r[0])); \
        float z0 = __builtin_amdgcn_rcpf(1.0f + __builtin_amdgcn_exp2f(d_z[0])); \
        float n0 = fmaf(-2.0f, __builtin_amdgcn_rcpf(1.0f +                   \
                   __builtin_amdgcn_exp2f(fmaf(r0, d_nh[0], d_nx[0]))), 1.0f); \
        hf0 = fmaf(z0, hf0 - n0, n0);                                         \
        float r1 = __builtin_amdgcn_rcpf(1.0f + __builtin_amdgcn_exp2f(d_r[1])); \
        float z1 = __builtin_amdgcn_rcpf(1.0f + __builtin_amdgcn_exp2f(d_z[1])); \
        float n1 = fmaf(-2.0f, __builtin_amdgcn_rcpf(1.0f +                   \
                   __builtin_amdgcn_exp2f(fmaf(r1, d_nh[1], d_nx[1]))), 1.0f); \
        hf1 = fmaf(z1, hf1 - n1, n1);                                         \
        float r2 = __builtin_amdgcn_rcpf(1.0f + __builtin_amdgcn_exp2f(d_r[2])); \
        float z2 = __builtin_amdgcn_rcpf(1.0f + __builtin_amdgcn_exp2f(d_z[2])); \
        float n2 = fmaf(-2.0f, __builtin_amdgcn_rcpf(1.0f +                   \
                   __builtin_amdgcn_exp2f(fmaf(r2, d_nh[2], d_nx[2]))), 1.0f); \
        hf2 = fmaf(z2, hf2 - n2, n2);                                         \
        float r3 = __builtin_amdgcn_rcpf(1.0f + __builtin_amdgcn_exp2f(d_r[3])); \
        float z3 = __builtin_amdgcn_rcpf(1.0f + __builtin_amdgcn_exp2f(d_z[3])); \
        float n3 = fmaf(-2.0f, __builtin_amdgcn_rcpf(1.0f +                   \
                   __builtin_amdgcn_exp2f(fmaf(r3, d_nh[3], d_nx[3]))), 1.0f); \
        hf3 = fmaf(z3, hf3 - n3, n3);                                         \
    } while (0)

    ISSUE(0);
    ISSUE(1);

    // Read-side swizzle constants (match write-side involution):
    // byte offset in batch's 1KB = (s*32 + (q&1)*16) ^ ((jb&7)<<4)
    const int swz   = (jb & 7) << 4;
    const int lobit = ((q & 1) * 16) ^ (swz & 16);
    const int swzhi = swz & 96;

#define RD(REC, S) (*(const floatx4*)((REC) + ((((S) & 31) * 32) ^ swzhi)))

    for (int c = 0; c < NC; ++c) {
        // Wait for chunk c's 16 loads; keep chunk c+1's 16 in flight.
        if (c == NC - 1) asm volatile("s_waitcnt vmcnt(0)" ::: "memory");
        else             asm volatile("s_waitcnt vmcnt(16)" ::: "memory");

        const char* myrec = &ldsbuf[c & 1][0] + jb * 1024 + lobit;

        floatx4 pfA = RD(myrec, 0);
        floatx4 pfB;
        // NOT unrolled: keep hot body small and L1 I-cache resident.
#pragma unroll 1
        for (int s = 0; s < TC; s += 2) {
            pfB = RD(myrec, s + 1);
            STEP(pfA);
            pfA = RD(myrec, s + 2);   // wraps to slot 0 on last iter (dead)
            STEP(pfB);
        }

        ISSUE(c + 2);   // after all reads of buf[c&1]
    }
#undef ISSUE
#undef STEP
#undef RD

    // ---- out[b] = dot(W_fc, h) + b_fc ; reduce across the 4 k-groups
    float p = hf0 * W_fc[4 * q + 0];
    p = fmaf(hf1, W_fc[4 * q + 1], p);
    p = fmaf(hf2, W_fc[4 * q + 2], p);
    p = fmaf(hf3, W_fc[4 * q + 3], p);
    p += __shfl_xor(p, 16);
    p += __shfl_xor(p, 32);
    if (q == 0) out[b0 + jb] = p + b_fc[0];
}

extern "C" void kernel_launch(void* const* d_in, const int* in_sizes, int n_in,
                              void* d_out, int out_size, void* d_ws, size_t ws_size,
                              hipStream_t stream) {
    const float* x    = (const float*)d_in[0];
    const float* W_ih = (const float*)d_in[1];
    const float* W_hh = (const float*)d_in[2];
    const float* b_ih = (const float*)d_in[3];
    const float* b_hh = (const float*)d_in[4];
    const float* W_fc = (const float*)d_in[5];
    const float* b_fc = (const float*)d_in[6];
    float* out = (float*)d_out;

    dim3 grid(BB / 16);   // one 64-lane wave per 16 batches
    dim3 block(64);
    gru_fwd_kernel<<<grid, block, 0, stream>>>(x, W_ih, W_hh, b_ih, b_hh, W_fc, b_fc, out);
}